// Round 7
// baseline (181.997 us; speedup 1.0000x reference)
//
#include <hip/hip_runtime.h>
#include <stdint.h>

#define N_CODES 65536
#define CB_DIM 8
#define B_ROWS 16
#define X_COLS 2048
#define M_ROWS 4096            // 16*2048/8
#define RPB 8                  // rows per argmin block
#define AT 1024                // argmin threads/block: 16 waves, 2 blk/CU -> 8 waves/SIMD

// workspace byte offsets (unchanged footprint: 2,507,008 B — no ws growth)
#define WS_SCALE 0             // 16 f32
#define WS_IDX   256           // 4096 i32
#define WS_U     16640         // 32768 f32  — holds nu = -2*(x/scale)
#define WS_SUMS  147712        // 65536*8 f32
#define WS_CNT   2244864       // 65536 f32

// distance + min-track for one code against 8 rows. nu[] values are loaded
// from global via a UNIFORM address -> s_load -> SGPRs (verified rounds 5/6:
// SGPR_Count 96, VGPR_Count 36-40, absmax 0.0). Each fma reads exactly one
// SGPR source (legal). fma chain order unchanged since round 0 -> bit-identical.
#define CODE_BODY(C0, C1, NIDX)                                            \
    {                                                                      \
        float hn = (C0).x * (C0).x;                                        \
        hn = fmaf((C0).y, (C0).y, hn);                                     \
        hn = fmaf((C0).z, (C0).z, hn);                                     \
        hn = fmaf((C0).w, (C0).w, hn);                                     \
        hn = fmaf((C1).x, (C1).x, hn);                                     \
        hn = fmaf((C1).y, (C1).y, hn);                                     \
        hn = fmaf((C1).z, (C1).z, hn);                                     \
        hn = fmaf((C1).w, (C1).w, hn);                                     \
        _Pragma("unroll")                                                  \
        for (int r = 0; r < RPB; r++) {                                    \
            float d = hn;                                                  \
            d = fmaf(nu[r * 8 + 0], (C0).x, d);                            \
            d = fmaf(nu[r * 8 + 1], (C0).y, d);                            \
            d = fmaf(nu[r * 8 + 2], (C0).z, d);                            \
            d = fmaf(nu[r * 8 + 3], (C0).w, d);                            \
            d = fmaf(nu[r * 8 + 4], (C1).x, d);                            \
            d = fmaf(nu[r * 8 + 5], (C1).y, d);                            \
            d = fmaf(nu[r * 8 + 6], (C1).z, d);                            \
            d = fmaf(nu[r * 8 + 7], (C1).w, d);                            \
            if (d < best[r]) { best[r] = d; bidx[r] = (NIDX); }            \
        }                                                                  \
    }

// ---------------- prep: per-row scale + nu = -2*(x/scale) ----------------
// Reduction order is VERBATIM the passing kernel's -> bit-identical scale.
__global__ __launch_bounds__(256) void prep_kernel(const float* __restrict__ x,
                                                   float* __restrict__ scale_out,
                                                   float* __restrict__ nuout) {
    int tid = threadIdx.x;
    int xr = blockIdx.x;                               // 0..15
    const float4* xv = (const float4*)(x + xr * X_COLS);
    float4 q0 = xv[tid];
    float4 q1 = xv[tid + 256];
    float s = fabsf(q0.x) + fabsf(q0.y) + fabsf(q0.z) + fabsf(q0.w)
            + fabsf(q1.x) + fabsf(q1.y) + fabsf(q1.z) + fabsf(q1.w);
    #pragma unroll
    for (int off = 32; off > 0; off >>= 1) s += __shfl_down(s, off, 64);
    __shared__ float ls[4];
    __shared__ float scale_sh;
    int wave = tid >> 6, lane = tid & 63;
    if (lane == 0) ls[wave] = s;
    __syncthreads();
    if (tid == 0) {
        float t = (ls[0] + ls[1] + ls[2] + ls[3]) * (1.0f / (float)X_COLS);
        scale_sh = t;
        scale_out[xr] = t;
    }
    __syncthreads();
    float scale = scale_sh;

    // nu = -2*(x/scale): same op composition as the passing kernels.
    float4 n0, n1;
    n0.x = -2.0f * (q0.x / scale);  n0.y = -2.0f * (q0.y / scale);
    n0.z = -2.0f * (q0.z / scale);  n0.w = -2.0f * (q0.w / scale);
    n1.x = -2.0f * (q1.x / scale);  n1.y = -2.0f * (q1.y / scale);
    n1.z = -2.0f * (q1.z / scale);  n1.w = -2.0f * (q1.w / scale);
    float4* np = (float4*)(nuout + xr * X_COLS);
    np[tid]       = n0;
    np[tid + 256] = n1;
}

// ---------------- argmin over the full codebook ----------------
// ROUND-7 CHANGE (the only one): 1024 threads/block. Occupancy ladder so far:
// 2 waves/SIMD -> 120us (VALUBusy 74), 4 -> 95us (67). Grid stays 512 blocks
// (L2 codebook traffic stays 1 GB); 16 waves/block x 2 blk/CU = 8 waves/SIMD
// = 100% nominal. Resources: VGPR 36<=64, SGPR 96<=~100 (the marginal one,
// hence launch_bounds(.,8)), LDS 64KB x2 <= 160KB. Numerics bit-identical:
// same fma chains, coverage tid+1024k, same u64 tie-break.
__global__ __launch_bounds__(AT, 8) void argmin_kernel(const float* __restrict__ cb,
                                                       const float* __restrict__ nuarr,
                                                       int* __restrict__ indices,
                                                       float* __restrict__ sums,
                                                       float* __restrict__ counts) {
    int tid = threadIdx.x;
    int m0 = blockIdx.x * RPB;

    // 64 wave-uniform nu via uniform-address loads -> s_load -> SGPRs.
    const float* __restrict__ up = nuarr + (size_t)m0 * CB_DIM;
    float nu[RPB * CB_DIM];
    #pragma unroll
    for (int i = 0; i < RPB * CB_DIM; i++) nu[i] = up[i];

    float best[RPB];
    int   bidx[RPB];
    #pragma unroll
    for (int r = 0; r < RPB; r++) { best[r] = 3.4e38f; bidx[r] = 0; }

    // ---- 4-wide ping-pong (structure verified absmax 0.0 in rounds 5/6).
    // Coverage: tid + AT*k, k=0..63. 16 groups of 4; loop 15 + peel.
    // Max prefetch: j=14 -> n+7*AT = tid+57344+7168 <= 65535.
    const float4* cp = (const float4*)cb;
    int n = tid;
    float4 a0 = cp[2 * n],            a1 = cp[2 * n + 1];
    float4 b0 = cp[2 * (n + AT)],     b1 = cp[2 * (n + AT) + 1];
    float4 c0 = cp[2 * (n + 2 * AT)], c1 = cp[2 * (n + 2 * AT) + 1];
    float4 d0 = cp[2 * (n + 3 * AT)], d1 = cp[2 * (n + 3 * AT) + 1];

    for (int j = 0; j < 15; j++) {
        CODE_BODY(a0, a1, n)
        CODE_BODY(b0, b1, n + AT)
        a0 = cp[2 * (n + 4 * AT)]; a1 = cp[2 * (n + 4 * AT) + 1];
        b0 = cp[2 * (n + 5 * AT)]; b1 = cp[2 * (n + 5 * AT) + 1];
        CODE_BODY(c0, c1, n + 2 * AT)
        CODE_BODY(d0, d1, n + 3 * AT)
        c0 = cp[2 * (n + 6 * AT)]; c1 = cp[2 * (n + 6 * AT) + 1];
        d0 = cp[2 * (n + 7 * AT)]; d1 = cp[2 * (n + 7 * AT) + 1];
        n += 4 * AT;
    }
    CODE_BODY(a0, a1, n)
    CODE_BODY(b0, b1, n + AT)
    CODE_BODY(c0, c1, n + 2 * AT)
    CODE_BODY(d0, d1, n + 3 * AT)

    // ---- cross-thread reduce: (sortable(dist)<<32)|idx, u64-min ----
    __shared__ unsigned long long red[RPB][AT];        // 64 KB (static LDS limit)
    #pragma unroll
    for (int r = 0; r < RPB; r++) {
        unsigned int b = __float_as_uint(best[r]);
        unsigned int k = b ^ ((unsigned int)((int)b >> 31) | 0x80000000u);
        red[r][tid] = ((unsigned long long)k << 32) | (unsigned int)bidx[r];
    }
    for (int t = AT / 2; t > 0; t >>= 1) {
        __syncthreads();
        if (tid < t) {
            #pragma unroll
            for (int r = 0; r < RPB; r++) {
                unsigned long long a = red[r][tid], c = red[r][tid + t];
                if (c < a) red[r][tid] = c;
            }
        }
    }
    __syncthreads();

    // indices + zero sums/counts at selected codes (kernel boundary orders
    // the zeros before accum; duplicate zero-writes are benign)
    if (tid < RPB) {
        int idx = (int)(red[tid][0] & 0xFFFFFFFFull);
        indices[m0 + tid] = idx;
        counts[idx] = 0.f;
        float4 z = make_float4(0.f, 0.f, 0.f, 0.f);
        float4* sp = (float4*)(sums + (size_t)idx * CB_DIM);
        sp[0] = z;
        sp[1] = z;
    }
}

// ---------------- segment-sum via atomics (128 blocks, 1 thr/(m,k)) ----------------
// nuarr holds -2u; sums accumulate -2*sum(u) EXACTLY (power-of-two scaling
// commutes with fp rounding, any atomic order). gather compensates.
__global__ __launch_bounds__(256) void accum_kernel(const int* __restrict__ indices,
                                                    const float* __restrict__ nuarr,
                                                    float* __restrict__ sums,
                                                    float* __restrict__ counts) {
    int e = blockIdx.x * blockDim.x + threadIdx.x;     // 0..32767, one per (m,k)
    int m = e >> 3, k = e & 7;
    int idx = indices[m];
    if (k == 0) atomicAdd(&counts[idx], 1.0f);
    atomicAdd(&sums[(size_t)idx * CB_DIM + k], nuarr[e]);
}

// ---------------- gather + rescale ----------------
__global__ __launch_bounds__(256) void gather_kernel(const int* __restrict__ indices,
                                                     const float* __restrict__ sums,
                                                     const float* __restrict__ counts,
                                                     const float* __restrict__ scale,
                                                     float* __restrict__ out) {
    int e = blockIdx.x * blockDim.x + threadIdx.x;     // 0..32767
    if (e < B_ROWS * X_COLS) {
        int m = e >> 3, k = e & 7;
        int idx = indices[m];
        float c = counts[idx];
        c = c < 1.f ? 1.f : c;
        // sums = -2*S exactly; (-0.5f)*(sums/c) == S/c bit-exactly.
        out[e] = scale[e >> 11] * (-0.5f * (sums[(size_t)idx * CB_DIM + k] / c));
    }
}

extern "C" void kernel_launch(void* const* d_in, const int* in_sizes, int n_in,
                              void* d_out, int out_size, void* d_ws, size_t ws_size,
                              hipStream_t stream) {
    const float* x  = (const float*)d_in[0];           // [16,2048]
    const float* cb = (const float*)d_in[1];           // [65536,8]
    char* ws = (char*)d_ws;
    float* scale   = (float*)(ws + WS_SCALE);
    int*   indices = (int*)(ws + WS_IDX);
    float* nuarr   = (float*)(ws + WS_U);
    float* sums    = (float*)(ws + WS_SUMS);
    float* counts  = (float*)(ws + WS_CNT);
    float* out     = (float*)d_out;

    prep_kernel  <<<B_ROWS, 256, 0, stream>>>(x, scale, nuarr);
    argmin_kernel<<<M_ROWS / RPB, AT, 0, stream>>>(cb, nuarr, indices, sums, counts);
    accum_kernel <<<(M_ROWS * CB_DIM) / 256, 256, 0, stream>>>(indices, nuarr, sums, counts);
    gather_kernel<<<(B_ROWS * X_COLS) / 256, 256, 0, stream>>>(indices, sums, counts, scale, out);
}

// Round 8
// 181.019 us; speedup vs baseline: 1.0054x; 1.0054x over previous
//
#include <hip/hip_runtime.h>
#include <stdint.h>

#define N_CODES 65536
#define CB_DIM 8
#define B_ROWS 16
#define X_COLS 2048
#define M_ROWS 4096            // 16*2048/8
#define RPB 8                  // rows per argmin block
#define AT 512                 // argmin threads/block (8 waves; 4 blk/CU -> 8 waves/SIMD)

// workspace byte offsets (total 2,425,088 B <= proven 2,507,008 capacity).
// nu (=-2*x/scale, 128 KB) lives in d_out until gather overwrites it.
#define WS_SCALE 0             // 16 f32                       (ends 256, padded)
#define WS_PART  256           // 4096*2 u64 partial keys      (ends 65792)
#define WS_SUMS  65792         // 65536*8 f32                  (ends 2162944)
#define WS_CNT   2162944       // 65536 f32 (contiguous w/ sums, ends 2425088)

// distance + min-track for one code against 8 rows. nu[] comes from a
// UNIFORM global address -> s_load -> SGPRs (proven rounds 5/6: SGPR 96,
// VGPR 36, absmax 0.0). One SGPR source per v_fma (legal). fma chain order
// unchanged since round 0 -> bit-identical distances.
#define CODE_BODY(C0, C1, NIDX)                                            \
    {                                                                      \
        float hn = (C0).x * (C0).x;                                        \
        hn = fmaf((C0).y, (C0).y, hn);                                     \
        hn = fmaf((C0).z, (C0).z, hn);                                     \
        hn = fmaf((C0).w, (C0).w, hn);                                     \
        hn = fmaf((C1).x, (C1).x, hn);                                     \
        hn = fmaf((C1).y, (C1).y, hn);                                     \
        hn = fmaf((C1).z, (C1).z, hn);                                     \
        hn = fmaf((C1).w, (C1).w, hn);                                     \
        _Pragma("unroll")                                                  \
        for (int r = 0; r < RPB; r++) {                                    \
            float d = hn;                                                  \
            d = fmaf(nu[r * 8 + 0], (C0).x, d);                            \
            d = fmaf(nu[r * 8 + 1], (C0).y, d);                            \
            d = fmaf(nu[r * 8 + 2], (C0).z, d);                            \
            d = fmaf(nu[r * 8 + 3], (C0).w, d);                            \
            d = fmaf(nu[r * 8 + 4], (C1).x, d);                            \
            d = fmaf(nu[r * 8 + 5], (C1).y, d);                            \
            d = fmaf(nu[r * 8 + 6], (C1).z, d);                            \
            d = fmaf(nu[r * 8 + 7], (C1).w, d);                            \
            if (d < best[r]) { best[r] = d; bidx[r] = (NIDX); }            \
        }                                                                  \
    }

// ------- prep: per-row scale + nu = -2*(x/scale) (into OUT) + zero sums/counts -------
// Reduction order VERBATIM the passing kernels' -> bit-identical scale.
__global__ __launch_bounds__(256) void prep_kernel(const float* __restrict__ x,
                                                   float* __restrict__ scale_out,
                                                   float* __restrict__ nuout,
                                                   float4* __restrict__ zero_base) {
    int tid = threadIdx.x;
    int xr = blockIdx.x;                               // 0..15
    const float4* xv = (const float4*)(x + xr * X_COLS);
    float4 q0 = xv[tid];
    float4 q1 = xv[tid + 256];
    float s = fabsf(q0.x) + fabsf(q0.y) + fabsf(q0.z) + fabsf(q0.w)
            + fabsf(q1.x) + fabsf(q1.y) + fabsf(q1.z) + fabsf(q1.w);
    #pragma unroll
    for (int off = 32; off > 0; off >>= 1) s += __shfl_down(s, off, 64);
    __shared__ float ls[4];
    __shared__ float scale_sh;
    int wave = tid >> 6, lane = tid & 63;
    if (lane == 0) ls[wave] = s;
    __syncthreads();
    if (tid == 0) {
        float t = (ls[0] + ls[1] + ls[2] + ls[3]) * (1.0f / (float)X_COLS);
        scale_sh = t;
        scale_out[xr] = t;
    }
    __syncthreads();
    float scale = scale_sh;

    // nu = -2*(x/scale): same op composition as the passing kernels.
    float4 n0, n1;
    n0.x = -2.0f * (q0.x / scale);  n0.y = -2.0f * (q0.y / scale);
    n0.z = -2.0f * (q0.z / scale);  n0.w = -2.0f * (q0.w / scale);
    n1.x = -2.0f * (q1.x / scale);  n1.y = -2.0f * (q1.y / scale);
    n1.z = -2.0f * (q1.z / scale);  n1.w = -2.0f * (q1.w / scale);
    float4* np = (float4*)(nuout + xr * X_COLS);
    np[tid]       = n0;
    np[tid + 256] = n1;

    // zero sums+counts: 2,359,296 B = 147456 float4 over 4096 threads ->
    // 36 float4 each, stride-4096 (coalesced). Replaces a memset dispatch;
    // kernel boundary orders this before accum's atomics.
    float4 z = make_float4(0.f, 0.f, 0.f, 0.f);
    int base = blockIdx.x * 256 + tid;
    #pragma unroll
    for (int i = 0; i < 36; i++) zero_base[base + i * 4096] = z;
}

// ---------------- argmin: 2-way code split, partial winner per half ----------------
// ROUND-8 CHANGE: grid 1024 (512 row-groups x 2 halves), AT=512.
// L2 traffic invariant (1024 x 1MB = 1GB). 4 blk/CU -> 8 waves/SIMD with
// VGPR cap 64 (body needs ~36 -> NO spill; round-7's 16-wave blocks capped
// at 32 and spilled: WRITE_SIZE 6.4MB). LDS 32KB x4 = 128 <= 160.
__global__ __launch_bounds__(AT, 8) void argmin_kernel(const float* __restrict__ cb,
                                                       const float* __restrict__ nuarr,
                                                       unsigned long long* __restrict__ part) {
    int tid = threadIdx.x;
    int rg  = blockIdx.x >> 1;                         // row-group 0..511
    int h   = blockIdx.x & 1;                          // code-space half
    int m0  = rg * RPB;

    // 64 wave-uniform nu via uniform-address loads -> s_load -> SGPRs.
    const float* __restrict__ up = nuarr + (size_t)m0 * CB_DIM;
    float nu[RPB * CB_DIM];
    #pragma unroll
    for (int i = 0; i < RPB * CB_DIM; i++) nu[i] = up[i];

    float best[RPB];
    int   bidx[RPB];
    #pragma unroll
    for (int r = 0; r < RPB; r++) { best[r] = 3.4e38f; bidx[r] = 0; }

    // ---- 4-wide ping-pong over this half's 32768 codes.
    // Coverage: (h<<15) + tid + AT*k, k=0..63. 16 groups of 4; 15 + peel.
    // Max prefetch: j=14 -> n+7*AT = h*32768 + tid + 28672 + 3584 <= 65535.
    const float4* cp = (const float4*)cb;
    int n = (h << 15) + tid;
    float4 a0 = cp[2 * n],            a1 = cp[2 * n + 1];
    float4 b0 = cp[2 * (n + AT)],     b1 = cp[2 * (n + AT) + 1];
    float4 c0 = cp[2 * (n + 2 * AT)], c1 = cp[2 * (n + 2 * AT) + 1];
    float4 d0 = cp[2 * (n + 3 * AT)], d1 = cp[2 * (n + 3 * AT) + 1];

    for (int j = 0; j < 15; j++) {
        CODE_BODY(a0, a1, n)
        CODE_BODY(b0, b1, n + AT)
        a0 = cp[2 * (n + 4 * AT)]; a1 = cp[2 * (n + 4 * AT) + 1];
        b0 = cp[2 * (n + 5 * AT)]; b1 = cp[2 * (n + 5 * AT) + 1];
        CODE_BODY(c0, c1, n + 2 * AT)
        CODE_BODY(d0, d1, n + 3 * AT)
        c0 = cp[2 * (n + 6 * AT)]; c1 = cp[2 * (n + 6 * AT) + 1];
        d0 = cp[2 * (n + 7 * AT)]; d1 = cp[2 * (n + 7 * AT) + 1];
        n += 4 * AT;
    }
    CODE_BODY(a0, a1, n)
    CODE_BODY(b0, b1, n + AT)
    CODE_BODY(c0, c1, n + 2 * AT)
    CODE_BODY(d0, d1, n + 3 * AT)

    // ---- cross-thread reduce: (sortable(dist)<<32)|idx, u64-min ----
    __shared__ unsigned long long red[RPB][AT];        // 32 KB
    #pragma unroll
    for (int r = 0; r < RPB; r++) {
        unsigned int b = __float_as_uint(best[r]);
        unsigned int k = b ^ ((unsigned int)((int)b >> 31) | 0x80000000u);
        red[r][tid] = ((unsigned long long)k << 32) | (unsigned int)bidx[r];
    }
    for (int t = AT / 2; t > 0; t >>= 1) {
        __syncthreads();
        if (tid < t) {
            #pragma unroll
            for (int r = 0; r < RPB; r++) {
                unsigned long long a = red[r][tid], c = red[r][tid + t];
                if (c < a) red[r][tid] = c;
            }
        }
    }
    __syncthreads();

    // partial winner for this half; halves merged in accum/gather.
    // u64 key ordering preserves exact dist-then-smallest-index semantics.
    if (tid < RPB) part[(size_t)(m0 + tid) * 2 + h] = red[tid][0];
}

// ---------------- merge halves + segment-sum via atomics ----------------
// nuarr(=out) holds -2u; sums accumulate -2*sum(u) EXACTLY. gather compensates.
__global__ __launch_bounds__(256) void accum_kernel(const unsigned long long* __restrict__ part,
                                                    const float* __restrict__ nuarr,
                                                    float* __restrict__ sums,
                                                    float* __restrict__ counts) {
    int e = blockIdx.x * blockDim.x + threadIdx.x;     // 0..32767, one per (m,k)
    int m = e >> 3, k = e & 7;
    unsigned long long k0 = part[2 * m], k1 = part[2 * m + 1];
    unsigned long long kk = k1 < k0 ? k1 : k0;
    int idx = (int)(kk & 0xFFFFFFFFull);
    if (k == 0) atomicAdd(&counts[idx], 1.0f);
    atomicAdd(&sums[(size_t)idx * CB_DIM + k], nuarr[e]);
}

// ---------------- gather + rescale (overwrites out; nu no longer needed) ----------------
__global__ __launch_bounds__(256) void gather_kernel(const unsigned long long* __restrict__ part,
                                                     const float* __restrict__ sums,
                                                     const float* __restrict__ counts,
                                                     const float* __restrict__ scale,
                                                     float* __restrict__ out) {
    int e = blockIdx.x * blockDim.x + threadIdx.x;     // 0..32767
    int m = e >> 3, k = e & 7;
    unsigned long long k0 = part[2 * m], k1 = part[2 * m + 1];
    unsigned long long kk = k1 < k0 ? k1 : k0;
    int idx = (int)(kk & 0xFFFFFFFFull);
    float c = counts[idx];
    c = c < 1.f ? 1.f : c;
    // sums = -2*S exactly; (-0.5f)*(sums/c) == S/c bit-exactly.
    out[e] = scale[e >> 11] * (-0.5f * (sums[(size_t)idx * CB_DIM + k] / c));
}

extern "C" void kernel_launch(void* const* d_in, const int* in_sizes, int n_in,
                              void* d_out, int out_size, void* d_ws, size_t ws_size,
                              hipStream_t stream) {
    const float* x  = (const float*)d_in[0];           // [16,2048]
    const float* cb = (const float*)d_in[1];           // [65536,8]
    char* ws = (char*)d_ws;
    float* scale   = (float*)(ws + WS_SCALE);
    unsigned long long* part = (unsigned long long*)(ws + WS_PART);
    float* sums    = (float*)(ws + WS_SUMS);
    float* counts  = (float*)(ws + WS_CNT);
    float* out     = (float*)d_out;
    // nu = -2*(x/scale) is staged in d_out (32768 f32 = exactly out's size):
    // prep writes it, argmin s_loads it, accum reads it, gather overwrites it.
    // Every consumer is separated by a kernel boundary; out is fully
    // rewritten each replay -> graph-replay deterministic.
    float* nuarr = out;

    prep_kernel  <<<B_ROWS, 256, 0, stream>>>(x, scale, nuarr, (float4*)(ws + WS_SUMS));
    argmin_kernel<<<(M_ROWS / RPB) * 2, AT, 0, stream>>>(cb, nuarr, part);
    accum_kernel <<<(M_ROWS * CB_DIM) / 256, 256, 0, stream>>>(part, nuarr, sums, counts);
    gather_kernel<<<(B_ROWS * X_COLS) / 256, 256, 0, stream>>>(part, sums, counts, scale, out);
}

// Round 9
// 143.443 us; speedup vs baseline: 1.2688x; 1.2620x over previous
//
#include <hip/hip_runtime.h>
#include <stdint.h>

#define N_CODES 65536
#define CB_DIM 8
#define B_ROWS 16
#define X_COLS 2048
#define M_ROWS 4096            // 16*2048/8
#define RPB 8                  // rows per argmin block
#define AT 512                 // argmin threads/block (8 waves)

// workspace byte offsets (total 2,425,088 B <= proven 2,507,008 capacity).
// nu (=-2*x/scale, 128 KB) lives in d_out until gather overwrites it.
#define WS_SCALE 0             // 16 f32                       (ends 256, padded)
#define WS_PART  256           // 4096*2 u64 partial keys      (ends 65792)
#define WS_SUMS  65792         // 65536*8 f32                  (ends 2162944)
#define WS_CNT   2162944       // 65536 f32 (contiguous w/ sums, ends 2425088)

// distance + min-track for one code against 8 rows. nu[] comes from a
// UNIFORM global address -> s_load -> SGPRs (proven rounds 5/6/8: SGPR 80-96,
// absmax 0.0). One SGPR source per v_fma (legal). fma chain order unchanged
// since round 0 -> bit-identical distances.
#define CODE_BODY(C0, C1, NIDX)                                            \
    {                                                                      \
        float hn = (C0).x * (C0).x;                                        \
        hn = fmaf((C0).y, (C0).y, hn);                                     \
        hn = fmaf((C0).z, (C0).z, hn);                                     \
        hn = fmaf((C0).w, (C0).w, hn);                                     \
        hn = fmaf((C1).x, (C1).x, hn);                                     \
        hn = fmaf((C1).y, (C1).y, hn);                                     \
        hn = fmaf((C1).z, (C1).z, hn);                                     \
        hn = fmaf((C1).w, (C1).w, hn);                                     \
        _Pragma("unroll")                                                  \
        for (int r = 0; r < RPB; r++) {                                    \
            float d = hn;                                                  \
            d = fmaf(nu[r * 8 + 0], (C0).x, d);                            \
            d = fmaf(nu[r * 8 + 1], (C0).y, d);                            \
            d = fmaf(nu[r * 8 + 2], (C0).z, d);                            \
            d = fmaf(nu[r * 8 + 3], (C0).w, d);                            \
            d = fmaf(nu[r * 8 + 4], (C1).x, d);                            \
            d = fmaf(nu[r * 8 + 5], (C1).y, d);                            \
            d = fmaf(nu[r * 8 + 6], (C1).z, d);                            \
            d = fmaf(nu[r * 8 + 7], (C1).w, d);                            \
            if (d < best[r]) { best[r] = d; bidx[r] = (NIDX); }            \
        }                                                                  \
    }

// ------- prep: per-row scale + nu = -2*(x/scale) (into OUT) + zero sums/counts -------
// Reduction order VERBATIM the passing kernels' -> bit-identical scale.
__global__ __launch_bounds__(256) void prep_kernel(const float* __restrict__ x,
                                                   float* __restrict__ scale_out,
                                                   float* __restrict__ nuout,
                                                   float4* __restrict__ zero_base) {
    int tid = threadIdx.x;
    int xr = blockIdx.x;                               // 0..15
    const float4* xv = (const float4*)(x + xr * X_COLS);
    float4 q0 = xv[tid];
    float4 q1 = xv[tid + 256];
    float s = fabsf(q0.x) + fabsf(q0.y) + fabsf(q0.z) + fabsf(q0.w)
            + fabsf(q1.x) + fabsf(q1.y) + fabsf(q1.z) + fabsf(q1.w);
    #pragma unroll
    for (int off = 32; off > 0; off >>= 1) s += __shfl_down(s, off, 64);
    __shared__ float ls[4];
    __shared__ float scale_sh;
    int wave = tid >> 6, lane = tid & 63;
    if (lane == 0) ls[wave] = s;
    __syncthreads();
    if (tid == 0) {
        float t = (ls[0] + ls[1] + ls[2] + ls[3]) * (1.0f / (float)X_COLS);
        scale_sh = t;
        scale_out[xr] = t;
    }
    __syncthreads();
    float scale = scale_sh;

    // nu = -2*(x/scale): same op composition as the passing kernels.
    float4 n0, n1;
    n0.x = -2.0f * (q0.x / scale);  n0.y = -2.0f * (q0.y / scale);
    n0.z = -2.0f * (q0.z / scale);  n0.w = -2.0f * (q0.w / scale);
    n1.x = -2.0f * (q1.x / scale);  n1.y = -2.0f * (q1.y / scale);
    n1.z = -2.0f * (q1.z / scale);  n1.w = -2.0f * (q1.w / scale);
    float4* np = (float4*)(nuout + xr * X_COLS);
    np[tid]       = n0;
    np[tid + 256] = n1;

    // zero sums+counts: 2,359,296 B = 147456 float4 over 4096 threads ->
    // 36 float4 each, stride-4096 (coalesced). Kernel boundary orders this
    // before accum's atomics.
    float4 z = make_float4(0.f, 0.f, 0.f, 0.f);
    int base = blockIdx.x * 256 + tid;
    #pragma unroll
    for (int i = 0; i < 36; i++) zero_base[base + i * 4096] = z;
}

// ---------------- argmin: 2-way code split, partial winner per half ----------------
// ROUND-9 CHANGE (one token): __launch_bounds__(512, 4) instead of (512, 8).
// The min-waves arg only squeezes the ALLOCATOR (R7/R8: cap 64 -> compiler
// chose 32 -> spill bloat, dur*VALUBusy 111us vs R6's 64us for identical
// arithmetic). Hardware occupancy comes from ACTUAL usage + grid: at the
// compiler's natural ~36-44 VGPR (R5/R6 evidence) and 32KB LDS, 4 blocks/CU
// = 8 waves/SIMD pack on this 1024-block grid (R8 evidence: occ 60%).
__global__ __launch_bounds__(AT, 4) void argmin_kernel(const float* __restrict__ cb,
                                                       const float* __restrict__ nuarr,
                                                       unsigned long long* __restrict__ part) {
    int tid = threadIdx.x;
    int rg  = blockIdx.x >> 1;                         // row-group 0..511
    int h   = blockIdx.x & 1;                          // code-space half
    int m0  = rg * RPB;

    // 64 wave-uniform nu via uniform-address loads -> s_load -> SGPRs.
    const float* __restrict__ up = nuarr + (size_t)m0 * CB_DIM;
    float nu[RPB * CB_DIM];
    #pragma unroll
    for (int i = 0; i < RPB * CB_DIM; i++) nu[i] = up[i];

    float best[RPB];
    int   bidx[RPB];
    #pragma unroll
    for (int r = 0; r < RPB; r++) { best[r] = 3.4e38f; bidx[r] = 0; }

    // ---- 4-wide ping-pong over this half's 32768 codes.
    // Coverage: (h<<15) + tid + AT*k, k=0..63. 16 groups of 4; 15 + peel.
    // Max prefetch: j=14 -> n+7*AT = h*32768 + tid + 28672 + 3584 <= 65535.
    const float4* cp = (const float4*)cb;
    int n = (h << 15) + tid;
    float4 a0 = cp[2 * n],            a1 = cp[2 * n + 1];
    float4 b0 = cp[2 * (n + AT)],     b1 = cp[2 * (n + AT) + 1];
    float4 c0 = cp[2 * (n + 2 * AT)], c1 = cp[2 * (n + 2 * AT) + 1];
    float4 d0 = cp[2 * (n + 3 * AT)], d1 = cp[2 * (n + 3 * AT) + 1];

    for (int j = 0; j < 15; j++) {
        CODE_BODY(a0, a1, n)
        CODE_BODY(b0, b1, n + AT)
        a0 = cp[2 * (n + 4 * AT)]; a1 = cp[2 * (n + 4 * AT) + 1];
        b0 = cp[2 * (n + 5 * AT)]; b1 = cp[2 * (n + 5 * AT) + 1];
        CODE_BODY(c0, c1, n + 2 * AT)
        CODE_BODY(d0, d1, n + 3 * AT)
        c0 = cp[2 * (n + 6 * AT)]; c1 = cp[2 * (n + 6 * AT) + 1];
        d0 = cp[2 * (n + 7 * AT)]; d1 = cp[2 * (n + 7 * AT) + 1];
        n += 4 * AT;
    }
    CODE_BODY(a0, a1, n)
    CODE_BODY(b0, b1, n + AT)
    CODE_BODY(c0, c1, n + 2 * AT)
    CODE_BODY(d0, d1, n + 3 * AT)

    // ---- cross-thread reduce: (sortable(dist)<<32)|idx, u64-min ----
    __shared__ unsigned long long red[RPB][AT];        // 32 KB
    #pragma unroll
    for (int r = 0; r < RPB; r++) {
        unsigned int b = __float_as_uint(best[r]);
        unsigned int k = b ^ ((unsigned int)((int)b >> 31) | 0x80000000u);
        red[r][tid] = ((unsigned long long)k << 32) | (unsigned int)bidx[r];
    }
    for (int t = AT / 2; t > 0; t >>= 1) {
        __syncthreads();
        if (tid < t) {
            #pragma unroll
            for (int r = 0; r < RPB; r++) {
                unsigned long long a = red[r][tid], c = red[r][tid + t];
                if (c < a) red[r][tid] = c;
            }
        }
    }
    __syncthreads();

    // partial winner for this half; halves merged in accum/gather.
    // u64 key ordering preserves exact dist-then-smallest-index semantics.
    if (tid < RPB) part[(size_t)(m0 + tid) * 2 + h] = red[tid][0];
}

// ---------------- merge halves + segment-sum via atomics ----------------
// nuarr(=out) holds -2u; sums accumulate -2*sum(u) EXACTLY. gather compensates.
__global__ __launch_bounds__(256) void accum_kernel(const unsigned long long* __restrict__ part,
                                                    const float* __restrict__ nuarr,
                                                    float* __restrict__ sums,
                                                    float* __restrict__ counts) {
    int e = blockIdx.x * blockDim.x + threadIdx.x;     // 0..32767, one per (m,k)
    int m = e >> 3, k = e & 7;
    unsigned long long k0 = part[2 * m], k1 = part[2 * m + 1];
    unsigned long long kk = k1 < k0 ? k1 : k0;
    int idx = (int)(kk & 0xFFFFFFFFull);
    if (k == 0) atomicAdd(&counts[idx], 1.0f);
    atomicAdd(&sums[(size_t)idx * CB_DIM + k], nuarr[e]);
}

// ---------------- gather + rescale (overwrites out; nu no longer needed) ----------------
__global__ __launch_bounds__(256) void gather_kernel(const unsigned long long* __restrict__ part,
                                                     const float* __restrict__ sums,
                                                     const float* __restrict__ counts,
                                                     const float* __restrict__ scale,
                                                     float* __restrict__ out) {
    int e = blockIdx.x * blockDim.x + threadIdx.x;     // 0..32767
    int m = e >> 3, k = e & 7;
    unsigned long long k0 = part[2 * m], k1 = part[2 * m + 1];
    unsigned long long kk = k1 < k0 ? k1 : k0;
    int idx = (int)(kk & 0xFFFFFFFFull);
    float c = counts[idx];
    c = c < 1.f ? 1.f : c;
    // sums = -2*S exactly; (-0.5f)*(sums/c) == S/c bit-exactly.
    out[e] = scale[e >> 11] * (-0.5f * (sums[(size_t)idx * CB_DIM + k] / c));
}

extern "C" void kernel_launch(void* const* d_in, const int* in_sizes, int n_in,
                              void* d_out, int out_size, void* d_ws, size_t ws_size,
                              hipStream_t stream) {
    const float* x  = (const float*)d_in[0];           // [16,2048]
    const float* cb = (const float*)d_in[1];           // [65536,8]
    char* ws = (char*)d_ws;
    float* scale   = (float*)(ws + WS_SCALE);
    unsigned long long* part = (unsigned long long*)(ws + WS_PART);
    float* sums    = (float*)(ws + WS_SUMS);
    float* counts  = (float*)(ws + WS_CNT);
    float* out     = (float*)d_out;
    // nu = -2*(x/scale) is staged in d_out (32768 f32 = exactly out's size):
    // prep writes it, argmin s_loads it, accum reads it, gather overwrites it.
    // Every consumer is separated by a kernel boundary; out is fully
    // rewritten each replay -> graph-replay deterministic.
    float* nuarr = out;

    prep_kernel  <<<B_ROWS, 256, 0, stream>>>(x, scale, nuarr, (float4*)(ws + WS_SUMS));
    argmin_kernel<<<(M_ROWS / RPB) * 2, AT, 0, stream>>>(cb, nuarr, part);
    accum_kernel <<<(M_ROWS * CB_DIM) / 256, 256, 0, stream>>>(part, nuarr, sums, counts);
    gather_kernel<<<(B_ROWS * X_COLS) / 256, 256, 0, stream>>>(part, sums, counts, scale, out);
}

// Round 10
// 139.669 us; speedup vs baseline: 1.3031x; 1.0270x over previous
//
#include <hip/hip_runtime.h>
#include <stdint.h>

#define N_CODES 65536
#define CB_DIM 8
#define B_ROWS 16
#define X_COLS 2048
#define M_ROWS 4096            // 16*2048/8
#define RPB 8                  // rows per argmin block
#define AT 512                 // argmin threads/block (8 waves)
#define NWAVE (AT / 64)

// workspace byte offsets (total 2,425,088 B <= proven 2,507,008 capacity).
// nu (=-2*x/scale, 128 KB) lives in d_out until gather overwrites it.
#define WS_SCALE 0             // 16 f32                       (ends 256, padded)
#define WS_PART  256           // 4096*2 u64 partial keys      (ends 65792)
#define WS_SUMS  65792         // 65536*8 f32                  (ends 2162944)
#define WS_CNT   2162944       // 65536 f32 (contiguous w/ sums, ends 2425088)

// distance + min-track for one code against 8 rows. nu[] comes from a
// UNIFORM global address -> s_load -> SGPRs (proven rounds 5/6/9: SGPR 96,
// VGPR 36, absmax 0.0). One SGPR source per v_fma (legal). fma chain order
// unchanged since round 0 -> bit-identical distances.
#define CODE_BODY(C0, C1, NIDX)                                            \
    {                                                                      \
        float hn = (C0).x * (C0).x;                                        \
        hn = fmaf((C0).y, (C0).y, hn);                                     \
        hn = fmaf((C0).z, (C0).z, hn);                                     \
        hn = fmaf((C0).w, (C0).w, hn);                                     \
        hn = fmaf((C1).x, (C1).x, hn);                                     \
        hn = fmaf((C1).y, (C1).y, hn);                                     \
        hn = fmaf((C1).z, (C1).z, hn);                                     \
        hn = fmaf((C1).w, (C1).w, hn);                                     \
        _Pragma("unroll")                                                  \
        for (int r = 0; r < RPB; r++) {                                    \
            float d = hn;                                                  \
            d = fmaf(nu[r * 8 + 0], (C0).x, d);                            \
            d = fmaf(nu[r * 8 + 1], (C0).y, d);                            \
            d = fmaf(nu[r * 8 + 2], (C0).z, d);                            \
            d = fmaf(nu[r * 8 + 3], (C0).w, d);                            \
            d = fmaf(nu[r * 8 + 4], (C1).x, d);                            \
            d = fmaf(nu[r * 8 + 5], (C1).y, d);                            \
            d = fmaf(nu[r * 8 + 6], (C1).z, d);                            \
            d = fmaf(nu[r * 8 + 7], (C1).w, d);                            \
            if (d < best[r]) { best[r] = d; bidx[r] = (NIDX); }            \
        }                                                                  \
    }

// ------- prep: per-row scale + nu = -2*(x/scale) into OUT -------
// (sums/counts zeroing moved to argmin's zero-selected tail; prep's 16-block
// grid made the 2.36 MB zero pass a serial ~5-8 us bottleneck)
// Reduction order VERBATIM the passing kernels' -> bit-identical scale.
__global__ __launch_bounds__(256) void prep_kernel(const float* __restrict__ x,
                                                   float* __restrict__ scale_out,
                                                   float* __restrict__ nuout) {
    int tid = threadIdx.x;
    int xr = blockIdx.x;                               // 0..15
    const float4* xv = (const float4*)(x + xr * X_COLS);
    float4 q0 = xv[tid];
    float4 q1 = xv[tid + 256];
    float s = fabsf(q0.x) + fabsf(q0.y) + fabsf(q0.z) + fabsf(q0.w)
            + fabsf(q1.x) + fabsf(q1.y) + fabsf(q1.z) + fabsf(q1.w);
    #pragma unroll
    for (int off = 32; off > 0; off >>= 1) s += __shfl_down(s, off, 64);
    __shared__ float ls[4];
    __shared__ float scale_sh;
    int wave = tid >> 6, lane = tid & 63;
    if (lane == 0) ls[wave] = s;
    __syncthreads();
    if (tid == 0) {
        float t = (ls[0] + ls[1] + ls[2] + ls[3]) * (1.0f / (float)X_COLS);
        scale_sh = t;
        scale_out[xr] = t;
    }
    __syncthreads();
    float scale = scale_sh;

    // nu = -2*(x/scale): same op composition as the passing kernels.
    float4 n0, n1;
    n0.x = -2.0f * (q0.x / scale);  n0.y = -2.0f * (q0.y / scale);
    n0.z = -2.0f * (q0.z / scale);  n0.w = -2.0f * (q0.w / scale);
    n1.x = -2.0f * (q1.x / scale);  n1.y = -2.0f * (q1.y / scale);
    n1.z = -2.0f * (q1.z / scale);  n1.w = -2.0f * (q1.w / scale);
    float4* np = (float4*)(nuout + xr * X_COLS);
    np[tid]       = n0;
    np[tid + 256] = n1;
}

// ---------------- argmin: 2-way code split, partial winner per half ----------------
// ROUND-10 CHANGE: the 32 KB LDS tree-reduce is replaced by an in-register
// wave64 shuffle reduce + 512 B cross-wave finish. Diagnosis: R6 (nominal 4
// waves/SIMD) and R9 (nominal 8) ran at identical 95us / VALUBusy 67% -> the
// extra waves never co-scheduled; the 32 KB LDS block is the co-residency cap
// (coarse LDS allocation granule -> 2 blocks/CU). u64-min is commutative/
// associative and shfl_down returns own value out-of-range -> identical
// winner + smallest-index tie-break -> bit-identical output.
__global__ __launch_bounds__(AT, 4) void argmin_kernel(const float* __restrict__ cb,
                                                       const float* __restrict__ nuarr,
                                                       unsigned long long* __restrict__ part,
                                                       float* __restrict__ sums,
                                                       float* __restrict__ counts) {
    int tid = threadIdx.x;
    int rg  = blockIdx.x >> 1;                         // row-group 0..511
    int h   = blockIdx.x & 1;                          // code-space half
    int m0  = rg * RPB;

    // 64 wave-uniform nu via uniform-address loads -> s_load -> SGPRs.
    const float* __restrict__ up = nuarr + (size_t)m0 * CB_DIM;
    float nu[RPB * CB_DIM];
    #pragma unroll
    for (int i = 0; i < RPB * CB_DIM; i++) nu[i] = up[i];

    float best[RPB];
    int   bidx[RPB];
    #pragma unroll
    for (int r = 0; r < RPB; r++) { best[r] = 3.4e38f; bidx[r] = 0; }

    // ---- 4-wide ping-pong over this half's 32768 codes.
    // Coverage: (h<<15) + tid + AT*k, k=0..63. 16 groups of 4; 15 + peel.
    // Max prefetch: j=14 -> n+7*AT = h*32768 + tid + 28672 + 3584 <= 65535.
    const float4* cp = (const float4*)cb;
    int n = (h << 15) + tid;
    float4 a0 = cp[2 * n],            a1 = cp[2 * n + 1];
    float4 b0 = cp[2 * (n + AT)],     b1 = cp[2 * (n + AT) + 1];
    float4 c0 = cp[2 * (n + 2 * AT)], c1 = cp[2 * (n + 2 * AT) + 1];
    float4 d0 = cp[2 * (n + 3 * AT)], d1 = cp[2 * (n + 3 * AT) + 1];

    for (int j = 0; j < 15; j++) {
        CODE_BODY(a0, a1, n)
        CODE_BODY(b0, b1, n + AT)
        a0 = cp[2 * (n + 4 * AT)]; a1 = cp[2 * (n + 4 * AT) + 1];
        b0 = cp[2 * (n + 5 * AT)]; b1 = cp[2 * (n + 5 * AT) + 1];
        CODE_BODY(c0, c1, n + 2 * AT)
        CODE_BODY(d0, d1, n + 3 * AT)
        c0 = cp[2 * (n + 6 * AT)]; c1 = cp[2 * (n + 6 * AT) + 1];
        d0 = cp[2 * (n + 7 * AT)]; d1 = cp[2 * (n + 7 * AT) + 1];
        n += 4 * AT;
    }
    CODE_BODY(a0, a1, n)
    CODE_BODY(b0, b1, n + AT)
    CODE_BODY(c0, c1, n + 2 * AT)
    CODE_BODY(d0, d1, n + 3 * AT)

    // ---- in-register wave64 u64-min reduce (6 shfl rounds), ~240 VALU once ----
    unsigned long long key[RPB];
    #pragma unroll
    for (int r = 0; r < RPB; r++) {
        unsigned int b = __float_as_uint(best[r]);
        unsigned int kk = b ^ ((unsigned int)((int)b >> 31) | 0x80000000u);
        key[r] = ((unsigned long long)kk << 32) | (unsigned int)bidx[r];
    }
    #pragma unroll
    for (int off = 32; off > 0; off >>= 1) {
        #pragma unroll
        for (int r = 0; r < RPB; r++) {
            unsigned long long o = __shfl_down(key[r], off, 64);
            if (o < key[r]) key[r] = o;
        }
    }

    // ---- cross-wave finish: 8 waves x 8 rows x u64 = 512 B LDS ----
    __shared__ unsigned long long wred[NWAVE][RPB];
    int wave = tid >> 6, lane = tid & 63;
    if (lane == 0) {
        #pragma unroll
        for (int r = 0; r < RPB; r++) wred[wave][r] = key[r];
    }
    __syncthreads();

    // thread r < 8 finalizes row r: partial winner for this half + zero the
    // winner's sums/counts (final winner is one of the two halves' winners ->
    // guaranteed zeroed; zeroing a losing candidate is benign; kernel
    // boundary orders all zeros before accum's atomics).
    if (tid < RPB) {
        unsigned long long m = wred[0][tid];
        #pragma unroll
        for (int w = 1; w < NWAVE; w++) {
            unsigned long long o = wred[w][tid];
            if (o < m) m = o;
        }
        part[(size_t)(m0 + tid) * 2 + h] = m;
        int idx = (int)(m & 0xFFFFFFFFull);
        counts[idx] = 0.f;
        float4 z = make_float4(0.f, 0.f, 0.f, 0.f);
        float4* sp = (float4*)(sums + (size_t)idx * CB_DIM);
        sp[0] = z;
        sp[1] = z;
    }
}

// ---------------- merge halves + segment-sum via atomics ----------------
// nuarr(=out) holds -2u; sums accumulate -2*sum(u) EXACTLY. gather compensates.
__global__ __launch_bounds__(256) void accum_kernel(const unsigned long long* __restrict__ part,
                                                    const float* __restrict__ nuarr,
                                                    float* __restrict__ sums,
                                                    float* __restrict__ counts) {
    int e = blockIdx.x * blockDim.x + threadIdx.x;     // 0..32767, one per (m,k)
    int m = e >> 3, k = e & 7;
    unsigned long long k0 = part[2 * m], k1 = part[2 * m + 1];
    unsigned long long kk = k1 < k0 ? k1 : k0;
    int idx = (int)(kk & 0xFFFFFFFFull);
    if (k == 0) atomicAdd(&counts[idx], 1.0f);
    atomicAdd(&sums[(size_t)idx * CB_DIM + k], nuarr[e]);
}

// ---------------- gather + rescale (overwrites out; nu no longer needed) ----------------
__global__ __launch_bounds__(256) void gather_kernel(const unsigned long long* __restrict__ part,
                                                     const float* __restrict__ sums,
                                                     const float* __restrict__ counts,
                                                     const float* __restrict__ scale,
                                                     float* __restrict__ out) {
    int e = blockIdx.x * blockDim.x + threadIdx.x;     // 0..32767
    int m = e >> 3, k = e & 7;
    unsigned long long k0 = part[2 * m], k1 = part[2 * m + 1];
    unsigned long long kk = k1 < k0 ? k1 : k0;
    int idx = (int)(kk & 0xFFFFFFFFull);
    float c = counts[idx];
    c = c < 1.f ? 1.f : c;
    // sums = -2*S exactly; (-0.5f)*(sums/c) == S/c bit-exactly.
    out[e] = scale[e >> 11] * (-0.5f * (sums[(size_t)idx * CB_DIM + k] / c));
}

extern "C" void kernel_launch(void* const* d_in, const int* in_sizes, int n_in,
                              void* d_out, int out_size, void* d_ws, size_t ws_size,
                              hipStream_t stream) {
    const float* x  = (const float*)d_in[0];           // [16,2048]
    const float* cb = (const float*)d_in[1];           // [65536,8]
    char* ws = (char*)d_ws;
    float* scale   = (float*)(ws + WS_SCALE);
    unsigned long long* part = (unsigned long long*)(ws + WS_PART);
    float* sums    = (float*)(ws + WS_SUMS);
    float* counts  = (float*)(ws + WS_CNT);
    float* out     = (float*)d_out;
    // nu = -2*(x/scale) is staged in d_out (32768 f32 = exactly out's size):
    // prep writes it, argmin s_loads it, accum reads it, gather overwrites it.
    // Every consumer is separated by a kernel boundary; out is fully
    // rewritten each replay -> graph-replay deterministic.
    float* nuarr = out;

    prep_kernel  <<<B_ROWS, 256, 0, stream>>>(x, scale, nuarr);
    argmin_kernel<<<(M_ROWS / RPB) * 2, AT, 0, stream>>>(cb, nuarr, part, sums, counts);
    accum_kernel <<<(M_ROWS * CB_DIM) / 256, 256, 0, stream>>>(part, nuarr, sums, counts);
    gather_kernel<<<(B_ROWS * X_COLS) / 256, 256, 0, stream>>>(part, sums, counts, scale, out);
}